// Round 17
// baseline (15814.581 us; speedup 1.0000x reference)
//
#include <hip/hip_runtime.h>
#include <math.h>

#define TSTEPS 512
#define NBATCH 256
#define DLL 300
#define DAA 74
#define DVV 35
#define DX  409
#define DH  128
#define DMEM 256
#define CST 768   // 6*DH

typedef unsigned short u16;
typedef unsigned int   u32;
typedef float v2f __attribute__((ext_vector_type(2)));
typedef _Float16 h2 __attribute__((ext_vector_type(2)));

__device__ __forceinline__ float sigf(float x){ return 1.0f/(1.0f+expf(-x)); }

__device__ __forceinline__ float d2(u32 w, u32 x, float c){
  return __builtin_amdgcn_fdot2(__builtin_bit_cast(h2,w), __builtin_bit_cast(h2,x), c, false);
}

// host retile: dst[((kb*OUT/2 + cp)*2 + s)*8 + j] = fp16(src[(2cp+s)*IN + kb*8+j]), 0-pad
__global__ void cast_pair(const float* __restrict__ src, _Float16* __restrict__ dst,
                          int OUT, int IN, int INP){
  int e = blockIdx.x*blockDim.x + threadIdx.x;
  if (e >= OUT*INP) return;
  int OUTH = OUT>>1;
  int j = e & 7;
  int s = (e>>3)&1;
  int q = e>>4;
  int cp = q % OUTH;
  int kb = q / OUTH;
  int k = kb*8 + j;
  int o = 2*cp + s;
  float v = (k < IN) ? src[o*IN + k] : 0.f;
  dst[e] = (_Float16)v;
}

struct P {
  const float* x;
  const float *bih_l,*bhh_l,*bih_a,*bhh_a,*bih_v,*bhh_v;
  const float *a1b1,*a1b2,*a2b1,*a2b2,*g1b1,*g1b2,*g2b1,*g2b2;
  const float *ob1,*ow2,*ob2;
  const _Float16 *ihl,*hhl,*iha,*hha,*ihv,*hhv;
  const _Float16 *a1w1,*a1w2,*a2w1,*a2w2,*g1w1,*g1w2,*g2w1,*g2w2,*ow1;
  float* out;
};

// one unit: 2 cols x 8k x 2 rows = 32 MACs via 16 dot2; wa=col0 8k fp16, wb=col1
__device__ __forceinline__ void unitc(uint4 wa, uint4 wb, uint4 xa, uint4 xb,
    float&a00,float&a01,float&a10,float&a11){
  a00=d2(wa.x,xa.x,a00); a01=d2(wa.x,xb.x,a01); a10=d2(wb.x,xa.x,a10); a11=d2(wb.x,xb.x,a11);
  a00=d2(wa.y,xa.y,a00); a01=d2(wa.y,xb.y,a01); a10=d2(wb.y,xa.y,a10); a11=d2(wb.y,xb.y,a11);
  a00=d2(wa.z,xa.z,a00); a01=d2(wa.z,xb.z,a01); a10=d2(wb.z,xa.z,a10); a11=d2(wb.z,xb.z,a11);
  a00=d2(wa.w,xa.w,a00); a01=d2(wa.w,xb.w,a01); a10=d2(wb.w,xa.w,a10); a11=d2(wb.w,xb.w,a11);
}

// Symmetric double-buffered ring: 2 units of WEIGHTS and 2 units of ACTS live
// and prefetched 2 units ahead (8 weight uint4 + 8 act uint4 in flight).
// NKB = number of 8k units (even, >=4). OUTH = OUT/2 (uint4 stride per kb = 2*OUTH).
template<int NKB, int OUTH>
__device__ __forceinline__ void sweep2(const uint4* __restrict__ wp,
    const _Float16* __restrict__ r0, const _Float16* __restrict__ r1,
    float&a00,float&a01,float&a10,float&a11){
  static_assert(NKB>=4 && (NKB&1)==0, "NKB even >=4");
  const int S = OUTH*2;
  uint4 p0a=wp[0], p0b=wp[1], p1a=wp[S], p1b=wp[S+1];
  uint4 xa0=*(const uint4*)(r0),   xb0=*(const uint4*)(r1);
  uint4 xa1=*(const uint4*)(r0+8), xb1=*(const uint4*)(r1+8);
  const uint4* wn = wp + 2*S;
  int u=0;
  #pragma unroll 1
  for (; u+2<NKB; u+=2){
    uint4 n0a=wn[0], n0b=wn[1], n1a=wn[S], n1b=wn[S+1]; wn += 2*S;
    uint4 ya=*(const uint4*)(r0+(u+2)*8), yb=*(const uint4*)(r1+(u+2)*8);
    uint4 za=*(const uint4*)(r0+(u+3)*8), zb=*(const uint4*)(r1+(u+3)*8);
    unitc(p0a,p0b,xa0,xb0,a00,a01,a10,a11);
    unitc(p1a,p1b,xa1,xb1,a00,a01,a10,a11);
    p0a=n0a; p0b=n0b; p1a=n1a; p1b=n1b;
    xa0=ya; xb0=yb; xa1=za; xb1=zb;
  }
  unitc(p0a,p0b,xa0,xb0,a00,a01,a10,a11);
  unitc(p1a,p1b,xa1,xb1,a00,a01,a10,a11);
}

// padded x col -> feature (or -1). L:[0,320) A:[320,448) V:[448,512)
__device__ __forceinline__ int xfeat(int k){
  if (k < 300) return k;
  if (k < 320) return -1;
  if (k < 394) return k-20;
  if (k < 448) return -1;
  if (k < 483) return k-74;
  return -1;
}

__global__ void __launch_bounds__(512, 2)
mfn_persistent(P p){
  __shared__ __align__(16) _Float16 s_x[1024];    // [r][512] padded fp16
  __shared__ __align__(16) _Float16 s_h[768];     // [(m*2+r)][128]
  __shared__ __align__(16) _Float16 s_cs[1536];   // [r][768] cstar fp16
  __shared__ __align__(16) _Float16 s_z[512];     // [r][256]
  __shared__ __align__(16) _Float16 s_at[2048];   // [r][att768|mem256]
  __shared__ __align__(16) _Float16 s_z2[1536];   // [r][mat*256+col]
  __shared__ __align__(16) _Float16 s_last[1280]; // [r][640]
  __shared__ __align__(16) float s_c2[768];       // fp32 cell state master
  __shared__ __align__(16) float s_csf[1536];     // fp32 cstar (for attended)
  __shared__ __align__(16) float s_mem[512];      // fp32 mem master
  __shared__ __align__(16) float s_p[6144];       // fp32 partials
  __shared__ __align__(16) float s_bl[3][512];
  __shared__ __align__(16) float s_a1b1[256];
  __shared__ __align__(16) float s_a1b2[768];
  __shared__ __align__(16) float s_b6[6][256];    // a2b1,g1b1,g2b1,a2b2,g1b2,g2b2
  __shared__ float s_red[16];

  const int tid = threadIdx.x;
  const int n0  = blockIdx.x*2;

  // ---- init ----
  s_bl[0][tid]=p.bih_l[tid]+p.bhh_l[tid];
  s_bl[1][tid]=p.bih_a[tid]+p.bhh_a[tid];
  s_bl[2][tid]=p.bih_v[tid]+p.bhh_v[tid];
  s_mem[tid]=0.f;
  if (tid < 256){
    s_a1b1[tid]=p.a1b1[tid];
    s_b6[0][tid]=p.a2b1[tid]; s_b6[1][tid]=p.g1b1[tid]; s_b6[2][tid]=p.g2b1[tid];
    s_b6[3][tid]=p.a2b2[tid]; s_b6[4][tid]=p.g1b2[tid]; s_b6[5][tid]=p.g2b2[tid];
  }
  for (int i=tid;i<768;i+=512){ s_a1b2[i]=p.a1b2[i]; s_c2[i]=0.f; s_h[i]=(_Float16)0.f; }
  for (int i=tid;i<1024;i+=512){
    int r=i>>9, k=i&511, f=xfeat(k);
    float v = (f>=0)? p.x[(size_t)(n0+r)*DX + f] : 0.f;
    s_x[i]=(_Float16)v;
  }
  __syncthreads();

  for (int t=0; t<TSTEPS; t++){
    // ===== P1: LSTM gates. cp=tid&255 col-pair of OUT=512, kh=tid>>8 K-half =====
    {
      const int cp=tid&255, kh=tid>>8;
      float a00,a01,a10,a11;
      // L
      a00=0.f;a01=0.f;a10=0.f;a11=0.f;
      sweep2<20,256>((const uint4*)p.ihl + kh*20*512 + cp*2, s_x+kh*160,     s_x+512+kh*160, a00,a01,a10,a11);
      sweep2< 8,256>((const uint4*)p.hhl + kh*8*512  + cp*2, s_h+kh*64,      s_h+128+kh*64,  a00,a01,a10,a11);
      *(v2f*)&s_p[        kh*1024 +       2*cp] = (v2f){a00,a10};
      *(v2f*)&s_p[        kh*1024 + 512 + 2*cp] = (v2f){a01,a11};
      // A
      a00=0.f;a01=0.f;a10=0.f;a11=0.f;
      sweep2< 8,256>((const uint4*)p.iha + kh*8*512 + cp*2, s_x+320+kh*64,  s_x+832+kh*64,  a00,a01,a10,a11);
      sweep2< 8,256>((const uint4*)p.hha + kh*8*512 + cp*2, s_h+256+kh*64,  s_h+384+kh*64,  a00,a01,a10,a11);
      *(v2f*)&s_p[2048 + kh*1024 +       2*cp] = (v2f){a00,a10};
      *(v2f*)&s_p[2048 + kh*1024 + 512 + 2*cp] = (v2f){a01,a11};
      // V
      a00=0.f;a01=0.f;a10=0.f;a11=0.f;
      sweep2< 4,256>((const uint4*)p.ihv + kh*4*512 + cp*2, s_x+448+kh*32,  s_x+960+kh*32,  a00,a01,a10,a11);
      sweep2< 8,256>((const uint4*)p.hhv + kh*8*512 + cp*2, s_h+512+kh*64,  s_h+640+kh*64,  a00,a01,a10,a11);
      *(v2f*)&s_p[4096 + kh*1024 +       2*cp] = (v2f){a00,a10};
      *(v2f*)&s_p[4096 + kh*1024 + 512 + 2*cp] = (v2f){a01,a11};
    }
    __syncthreads();                               // B1

    // ===== P2: LSTM activations (768 tasks) =====
    for (int task=tid; task<768; task+=512){
      int m=task>>8, rem=task&255, u=rem>>1, r=rem&1;
      const float* pm = s_p + m*2048 + r*512;
      const float* bl = s_bl[m];
      float g0 = bl[u]     + pm[u]     + pm[1024+u];
      float g1 = bl[128+u] + pm[128+u] + pm[1024+128+u];
      float g2 = bl[256+u] + pm[256+u] + pm[1024+256+u];
      float g3 = bl[384+u] + pm[384+u] + pm[1024+384+u];
      float ig=sigf(g0), fg=sigf(g1), gg=tanhf(g2), og=sigf(g3);
      float co = s_c2[(m*2+r)*128+u];
      float c  = fg*co + ig*gg;
      float h  = og*tanhf(c);
      s_c2[(m*2+r)*128+u]=c;
      s_h[(m*2+r)*128+u]=(_Float16)h;
      s_csf[r*768 + m*128+u]     = co;  s_cs[r*768 + m*128+u]     = (_Float16)co;
      s_csf[r*768 + 384+m*128+u] = c;   s_cs[r*768 + 384+m*128+u] = (_Float16)c;
    }
    __syncthreads();                               // B2

    // ===== P3: att1_W1 (256,768) on ALL 512 threads (cp128 x kh4, 24 units) =====
    {
      int cp=tid&127, kh=tid>>7;
      float a00=0.f,a01=0.f,a10=0.f,a11=0.f;
      sweep2<24,128>((const uint4*)p.a1w1 + kh*24*256 + cp*2, s_cs+kh*192, s_cs+768+kh*192, a00,a01,a10,a11);
      *(v2f*)&s_p[kh*512 +       2*cp] = (v2f){a00,a10};
      *(v2f*)&s_p[kh*512 + 256 + 2*cp] = (v2f){a01,a11};
    }
    __syncthreads();                               // B3

    // ===== P4: z1 finalize (4 kh segs) =====
    {
      int c=tid&255, r=tid>>8;
      float z = s_a1b1[c] + s_p[r*256+c] + s_p[512+r*256+c]
                          + s_p[1024+r*256+c] + s_p[1536+r*256+c];
      s_z[r*256+c] = (_Float16)fmaxf(z,0.f);
    }
    __syncthreads();                               // B4

    // ===== P5: att1_W2 (768,256): 384 pair-threads full-K; idle 128 prefetch x(t+1) =====
    if (tid < 384){
      float a00=0.f,a01=0.f,a10=0.f,a11=0.f;
      sweep2<32,384>((const uint4*)p.a1w2 + tid*2, s_z, s_z+256, a00,a01,a10,a11);
      *(v2f*)&s_p[      2*tid] = (v2f){a00,a10};
      *(v2f*)&s_p[768 + 2*tid] = (v2f){a01,a11};
    } else if (t+1 < TSTEPS){
      const float* __restrict__ xb = p.x + (size_t)(t+1)*NBATCH*DX;
      #pragma unroll
      for (int q=0;q<8;q++){
        int i2 = (tid-384) + q*128;
        int r=i2>>9, k=i2&511, f=xfeat(k);
        if (f>=0) s_x[i2] = (_Float16)xb[(size_t)(n0+r)*DX + f];
      }
    }
    __syncthreads();                               // B5

    // ===== softmax + attended =====
    {
      int col=tid&255, rr=tid>>8;
      float s0 = s_a1b2[col]     + s_p[rr*768+col];
      float s1 = s_a1b2[256+col] + s_p[rr*768+256+col];
      float s2 = s_a1b2[512+col] + s_p[rr*768+512+col];
      float mx=fmaxf(fmaxf(s0,s1),s2);
      for (int off=32; off; off>>=1) mx=fmaxf(mx,__shfl_down(mx,off));
      if ((tid&63)==0) s_red[tid>>6]=mx;
      __syncthreads();                             // B6
      float m = fmaxf(fmaxf(s_red[rr*4],s_red[rr*4+1]),fmaxf(s_red[rr*4+2],s_red[rr*4+3]));
      float e0=expf(s0-m), e1=expf(s1-m), e2=expf(s2-m);
      float ss=e0+e1+e2;
      for (int off=32; off; off>>=1) ss+=__shfl_down(ss,off);
      if ((tid&63)==0) s_red[8+(tid>>6)]=ss;
      s_at[rr*1024 + 768 + col] = (_Float16)s_mem[rr*256+col];
      __syncthreads();                             // B7
      float inv=1.f/(s_red[8+rr*4]+s_red[8+rr*4+1]+s_red[8+rr*4+2]+s_red[8+rr*4+3]);
      s_at[rr*1024 + col]       = (_Float16)(e0*inv*s_csf[rr*768+col]);
      s_at[rr*1024 + 256 + col] = (_Float16)(e1*inv*s_csf[rr*768+256+col]);
      s_at[rr*1024 + 512 + col] = (_Float16)(e2*inv*s_csf[rr*768+512+col]);
    }
    __syncthreads();                               // B8

    // ===== P7a: a2w1 (K=768) on 512 thr (cp128 x kh4, 24u) =====
    // ===== P7b: g1w1/g2w1 (K=1024) each on 256 thr (cp128 x kh2, 64u) =====
    {
      int cp=tid&127, kh4=tid>>7;
      float a00=0.f,a01=0.f,a10=0.f,a11=0.f;
      sweep2<24,128>((const uint4*)p.a2w1 + kh4*24*256 + cp*2, s_at+kh4*192, s_at+1024+kh4*192, a00,a01,a10,a11);
      *(v2f*)&s_p[kh4*512 +       2*cp] = (v2f){a00,a10};
      *(v2f*)&s_p[kh4*512 + 256 + 2*cp] = (v2f){a01,a11};
      int mg = tid>>8, kh = (tid>>7)&1;
      const _Float16* W = mg ? p.g2w1 : p.g1w1;
      a00=0.f;a01=0.f;a10=0.f;a11=0.f;
      sweep2<64,128>((const uint4*)W + kh*64*256 + cp*2, s_at+kh*512, s_at+1024+kh*512, a00,a01,a10,a11);
      *(v2f*)&s_p[2048 + mg*1024 + kh*512 +       2*cp] = (v2f){a00,a10};
      *(v2f*)&s_p[2048 + mg*1024 + kh*512 + 256 + 2*cp] = (v2f){a01,a11};
    }
    __syncthreads();                               // B9

    // ===== P8: z2 finalize (1536 tasks) =====
    for (int i=tid;i<1536;i+=512){
      int mu=i>>9, rem=i&511, r=rem>>8, c=rem&255;
      float v;
      if (mu==0)
        v = s_b6[0][c] + s_p[r*256+c] + s_p[512+r*256+c]
                       + s_p[1024+r*256+c] + s_p[1536+r*256+c];
      else {
        const float* q = s_p + 2048 + (mu-1)*1024;
        v = s_b6[mu][c] + q[r*256+c] + q[512+r*256+c];
      }
      s_z2[r*768 + mu*256 + c] = (_Float16)fmaxf(v,0.f);
    }
    __syncthreads();                               // B10

    // ===== P9: a2w2/g1w2/g2w2 (K=256 each); 3 groups x 128 pair-threads =====
    {
      int m4=tid>>7, cp=tid&127;
      if (m4<3){
        const _Float16* W = (m4==0)? p.a2w2 : ((m4==1)? p.g1w2 : p.g2w2);
        float a00=0.f,a01=0.f,a10=0.f,a11=0.f;
        sweep2<32,128>((const uint4*)W + cp*2, s_z2+m4*256, s_z2+768+m4*256, a00,a01,a10,a11);
        *(v2f*)&s_p[m4*512 +       2*cp] = (v2f){a00,a10};
        *(v2f*)&s_p[m4*512 + 256 + 2*cp] = (v2f){a01,a11};
      }
    }
    __syncthreads();                               // B11

    // ===== P10: mem update =====
    {
      int c=tid&255, r=tid>>8;
      float ch  = s_b6[3][c] + s_p[r*256+c];
      float gm1 = s_b6[4][c] + s_p[512 + r*256+c];
      float gm2 = s_b6[5][c] + s_p[1024 + r*256+c];
      float mo = s_mem[r*256+c];
      s_mem[r*256+c] = sigf(gm1)*mo + sigf(gm2)*tanhf(ch);
    }
    __syncthreads();                               // B12
  }

  // ===== output MLP (K=640) =====
  for (int i=tid;i<1280;i+=512){
    int r=(i>=640)?1:0, j=i-r*640;
    _Float16 v = (j<384)? s_h[((j>>7)*2+r)*128 + (j&127)] : (_Float16)s_mem[r*256+(j-384)];
    s_last[r*640+j]=v;
  }
  __syncthreads();
  if (tid < 256){
    int cp=tid&127, kh=tid>>7;
    float a00=0.f,a01=0.f,a10=0.f,a11=0.f;
    sweep2<40,128>((const uint4*)p.ow1 + kh*40*256 + cp*2, s_last+kh*320, s_last+640+kh*320, a00,a01,a10,a11);
    *(v2f*)&s_p[kh*512 +       2*cp] = (v2f){a00,a10};
    *(v2f*)&s_p[kh*512 + 256 + 2*cp] = (v2f){a01,a11};
  }
  __syncthreads();
  {
    int c=tid&255, rr=tid>>8;
    float z = p.ob1[c] + s_p[rr*256+c] + s_p[512+rr*256+c];
    float pp = fmaxf(z,0.f)*p.ow2[c];
    for (int off=32; off; off>>=1) pp+=__shfl_down(pp,off);
    if ((tid&63)==0) s_red[tid>>6]=pp;
    __syncthreads();
    if (tid==0)   p.out[n0]   = s_red[0]+s_red[1]+s_red[2]+s_red[3]+p.ob2[0];
    if (tid==256) p.out[n0+1] = s_red[4]+s_red[5]+s_red[6]+s_red[7]+p.ob2[0];
  }
}

extern "C" void kernel_launch(void* const* d_in, const int* in_sizes, int n_in,
                              void* d_out, int out_size, void* d_ws, size_t ws_size,
                              hipStream_t stream){
  _Float16* ws = (_Float16*)d_ws;
  struct M { int src; size_t off; int OUT, IN, INP; };
  const M mats[15] = {
    { 5,       0, 512,  300, 320},  // Wih_l
    { 6,  163840, 512,  128, 128},  // Whh_l
    { 9,  229376, 512,   74, 128},  // Wih_a
    {10,  294912, 512,  128, 128},  // Whh_a
    {13,  360448, 512,   35,  64},  // Wih_v
    {14,  393216, 512,  128, 128},  // Whh_v
    {17,  458752, 256,  768, 768},  // att1_W1
    {19,  655360, 768,  256, 256},  // att1_W2
    {21,  851968, 256,  768, 768},  // att2_W1
    {23, 1048576, 256,  256, 256},  // att2_W2
    {25, 1114112, 256, 1024,1024},  // g1_W1
    {27, 1376256, 256,  256, 256},  // g1_W2
    {29, 1441792, 256, 1024,1024},  // g2_W1
    {31, 1703936, 256,  256, 256},  // g2_W2
    {33, 1769472, 256,  640, 640},  // out_W1
  };
  for (int i=0;i<15;i++){
    int total = mats[i].OUT*mats[i].INP;
    cast_pair<<<(total+255)/256, 256, 0, stream>>>(
        (const float*)d_in[mats[i].src], ws + mats[i].off,
        mats[i].OUT, mats[i].IN, mats[i].INP);
  }

  P p;
  p.x     = (const float*)d_in[0];
  p.bih_l = (const float*)d_in[7];  p.bhh_l = (const float*)d_in[8];
  p.bih_a = (const float*)d_in[11]; p.bhh_a = (const float*)d_in[12];
  p.bih_v = (const float*)d_in[15]; p.bhh_v = (const float*)d_in[16];
  p.a1b1  = (const float*)d_in[18]; p.a1b2  = (const float*)d_in[20];
  p.a2b1  = (const float*)d_in[22]; p.a2b2  = (const float*)d_in[24];
  p.g1b1  = (const float*)d_in[26]; p.g1b2  = (const float*)d_in[28];
  p.g2b1  = (const float*)d_in[30]; p.g2b2  = (const float*)d_in[32];
  p.ob1   = (const float*)d_in[34]; p.ow2   = (const float*)d_in[35];
  p.ob2   = (const float*)d_in[36];
  p.ihl   = ws + 0;       p.hhl  = ws + 163840;
  p.iha   = ws + 229376;  p.hha  = ws + 294912;
  p.ihv   = ws + 360448;  p.hhv  = ws + 393216;
  p.a1w1  = ws + 458752;  p.a1w2 = ws + 655360;
  p.a2w1  = ws + 851968;  p.a2w2 = ws + 1048576;
  p.g1w1  = ws + 1114112; p.g1w2 = ws + 1376256;
  p.g2w1  = ws + 1441792; p.g2w2 = ws + 1703936;
  p.ow1   = ws + 1769472;
  p.out   = (float*)d_out;

  mfn_persistent<<<NBATCH/2, 512, 0, stream>>>(p);
}

// Round 18
// 15308.206 us; speedup vs baseline: 1.0331x; 1.0331x over previous
//
#include <hip/hip_runtime.h>
#include <math.h>

#define TSTEPS 512
#define NBATCH 256
#define DLL 300
#define DAA 74
#define DVV 35
#define DX  409
#define DH  128
#define DMEM 256
#define CST 768   // 6*DH

typedef unsigned short u16;
typedef unsigned int   u32;
typedef float v2f __attribute__((ext_vector_type(2)));
typedef _Float16 h2 __attribute__((ext_vector_type(2)));

__device__ __forceinline__ float sigf(float x){ return 1.0f/(1.0f+expf(-x)); }

__device__ __forceinline__ float d2(u32 w, u32 x, float c){
  return __builtin_amdgcn_fdot2(__builtin_bit_cast(h2,w), __builtin_bit_cast(h2,x), c, false);
}

// host retile: dst[((kb*OUT/2 + cp)*2 + s)*8 + j] = fp16(src[(2cp+s)*IN + kb*8+j]), 0-pad
__global__ void cast_pair(const float* __restrict__ src, _Float16* __restrict__ dst,
                          int OUT, int IN, int INP){
  int e = blockIdx.x*blockDim.x + threadIdx.x;
  if (e >= OUT*INP) return;
  int OUTH = OUT>>1;
  int j = e & 7;
  int s = (e>>3)&1;
  int q = e>>4;
  int cp = q % OUTH;
  int kb = q / OUTH;
  int k = kb*8 + j;
  int o = 2*cp + s;
  float v = (k < IN) ? src[o*IN + k] : 0.f;
  dst[e] = (_Float16)v;
}

struct P {
  const float* x;
  const float *bih_l,*bhh_l,*bih_a,*bhh_a,*bih_v,*bhh_v;
  const float *a1b1,*a1b2,*a2b1,*a2b2,*g1b1,*g1b2,*g2b1,*g2b2;
  const float *ob1,*ow2,*ob2;
  const _Float16 *ihl,*hhl,*iha,*hha,*ihv,*hhv;
  const _Float16 *a1w1,*a1w2,*a2w1,*a2w2,*g1w1,*g1w2,*g2w1,*g2w2,*ow1;
  float* out;
};

// one unit: 2 cols x 8k x 2 rows = 32 MACs via 16 dot2; wa=col0 8k fp16, wb=col1
__device__ __forceinline__ void unitc(uint4 wa, uint4 wb, uint4 xa, uint4 xb,
    float&a00,float&a01,float&a10,float&a11){
  a00=d2(wa.x,xa.x,a00); a01=d2(wa.x,xb.x,a01); a10=d2(wb.x,xa.x,a10); a11=d2(wb.x,xb.x,a11);
  a00=d2(wa.y,xa.y,a00); a01=d2(wa.y,xb.y,a01); a10=d2(wb.y,xa.y,a10); a11=d2(wb.y,xb.y,a11);
  a00=d2(wa.z,xa.z,a00); a01=d2(wa.z,xb.z,a01); a10=d2(wb.z,xa.z,a10); a11=d2(wb.z,xb.z,a11);
  a00=d2(wa.w,xa.w,a00); a01=d2(wa.w,xb.w,a01); a10=d2(wb.w,xa.w,a10); a11=d2(wb.w,xb.w,a11);
}

// R9-shape ring at unit granularity: 2 units live, 2 prefetched (8 uint4 total).
// NKB = number of 8k units (even, >=4). OUTH = OUT/2 (uint4 stride per kb = 2*OUTH).
template<int NKB, int OUTH>
__device__ __forceinline__ void sweep2(const uint4* __restrict__ wp,
    const _Float16* __restrict__ r0, const _Float16* __restrict__ r1,
    float&a00,float&a01,float&a10,float&a11){
  static_assert(NKB>=4 && (NKB&1)==0, "NKB even >=4");
  const int S = OUTH*2;
  uint4 p0a=wp[0], p0b=wp[1], p1a=wp[S], p1b=wp[S+1];
  const uint4* wn = wp + 2*S;
  int u=0;
  #pragma unroll 1
  for (; u+2<NKB; u+=2){
    uint4 n0a=wn[0], n0b=wn[1], n1a=wn[S], n1b=wn[S+1]; wn += 2*S;
    uint4 xa=*(const uint4*)(r0+u*8), xb=*(const uint4*)(r1+u*8);
    unitc(p0a,p0b,xa,xb,a00,a01,a10,a11);
    xa=*(const uint4*)(r0+u*8+8); xb=*(const uint4*)(r1+u*8+8);
    unitc(p1a,p1b,xa,xb,a00,a01,a10,a11);
    p0a=n0a; p0b=n0b; p1a=n1a; p1b=n1b;
  }
  {
    uint4 xa=*(const uint4*)(r0+u*8), xb=*(const uint4*)(r1+u*8);
    unitc(p0a,p0b,xa,xb,a00,a01,a10,a11);
    xa=*(const uint4*)(r0+u*8+8); xb=*(const uint4*)(r1+u*8+8);
    unitc(p1a,p1b,xa,xb,a00,a01,a10,a11);
  }
}

// padded x col -> feature (or -1). L:[0,320) A:[320,448) V:[448,512)
__device__ __forceinline__ int xfeat(int k){
  if (k < 300) return k;
  if (k < 320) return -1;
  if (k < 394) return k-20;
  if (k < 448) return -1;
  if (k < 483) return k-74;
  return -1;
}

__global__ void __launch_bounds__(512)
mfn_persistent(P p){
  __shared__ __align__(16) _Float16 s_x[1024];    // [r][512] padded fp16
  __shared__ __align__(16) _Float16 s_h[768];     // [(m*2+r)][128]
  __shared__ __align__(16) _Float16 s_cs[1536];   // [r][768] cstar fp16
  __shared__ __align__(16) _Float16 s_z[512];     // [r][256]
  __shared__ __align__(16) _Float16 s_at[2048];   // [r][att768|mem256]
  __shared__ __align__(16) _Float16 s_z2[1536];   // [r][mat*256+col]
  __shared__ __align__(16) _Float16 s_last[1280]; // [r][640]
  __shared__ __align__(16) float s_c2[768];       // fp32 cell state master
  __shared__ __align__(16) float s_csf[1536];     // fp32 cstar (for attended)
  __shared__ __align__(16) float s_mem[512];      // fp32 mem master
  __shared__ __align__(16) float s_p[6144];       // fp32 partials
  __shared__ __align__(16) float s_bl[3][512];
  __shared__ __align__(16) float s_a1b1[256];
  __shared__ __align__(16) float s_a1b2[768];
  __shared__ __align__(16) float s_b6[6][256];    // a2b1,g1b1,g2b1,a2b2,g1b2,g2b2
  __shared__ float s_red[16];

  const int tid = threadIdx.x;
  const int n0  = blockIdx.x*2;

  // ---- init ----
  s_bl[0][tid]=p.bih_l[tid]+p.bhh_l[tid];
  s_bl[1][tid]=p.bih_a[tid]+p.bhh_a[tid];
  s_bl[2][tid]=p.bih_v[tid]+p.bhh_v[tid];
  s_mem[tid]=0.f;
  if (tid < 256){
    s_a1b1[tid]=p.a1b1[tid];
    s_b6[0][tid]=p.a2b1[tid]; s_b6[1][tid]=p.g1b1[tid]; s_b6[2][tid]=p.g2b1[tid];
    s_b6[3][tid]=p.a2b2[tid]; s_b6[4][tid]=p.g1b2[tid]; s_b6[5][tid]=p.g2b2[tid];
  }
  for (int i=tid;i<768;i+=512){ s_a1b2[i]=p.a1b2[i]; s_c2[i]=0.f; s_h[i]=(_Float16)0.f; }
  for (int i=tid;i<1024;i+=512){
    int r=i>>9, k=i&511, f=xfeat(k);
    float v = (f>=0)? p.x[(size_t)(n0+r)*DX + f] : 0.f;
    s_x[i]=(_Float16)v;
  }
  __syncthreads();

  for (int t=0; t<TSTEPS; t++){
    // ===== P1: LSTM gates. cp=tid&255 col-pair of OUT=512, kh=tid>>8 K-half =====
    {
      const int cp=tid&255, kh=tid>>8;
      float a00,a01,a10,a11;
      // L
      a00=0.f;a01=0.f;a10=0.f;a11=0.f;
      sweep2<20,256>((const uint4*)p.ihl + kh*20*512 + cp*2, s_x+kh*160,     s_x+512+kh*160, a00,a01,a10,a11);
      sweep2< 8,256>((const uint4*)p.hhl + kh*8*512  + cp*2, s_h+kh*64,      s_h+128+kh*64,  a00,a01,a10,a11);
      *(v2f*)&s_p[        kh*1024 +       2*cp] = (v2f){a00,a10};
      *(v2f*)&s_p[        kh*1024 + 512 + 2*cp] = (v2f){a01,a11};
      // A
      a00=0.f;a01=0.f;a10=0.f;a11=0.f;
      sweep2< 8,256>((const uint4*)p.iha + kh*8*512 + cp*2, s_x+320+kh*64,  s_x+832+kh*64,  a00,a01,a10,a11);
      sweep2< 8,256>((const uint4*)p.hha + kh*8*512 + cp*2, s_h+256+kh*64,  s_h+384+kh*64,  a00,a01,a10,a11);
      *(v2f*)&s_p[2048 + kh*1024 +       2*cp] = (v2f){a00,a10};
      *(v2f*)&s_p[2048 + kh*1024 + 512 + 2*cp] = (v2f){a01,a11};
      // V
      a00=0.f;a01=0.f;a10=0.f;a11=0.f;
      sweep2< 4,256>((const uint4*)p.ihv + kh*4*512 + cp*2, s_x+448+kh*32,  s_x+960+kh*32,  a00,a01,a10,a11);
      sweep2< 8,256>((const uint4*)p.hhv + kh*8*512 + cp*2, s_h+512+kh*64,  s_h+640+kh*64,  a00,a01,a10,a11);
      *(v2f*)&s_p[4096 + kh*1024 +       2*cp] = (v2f){a00,a10};
      *(v2f*)&s_p[4096 + kh*1024 + 512 + 2*cp] = (v2f){a01,a11};
    }
    __syncthreads();                               // B1

    // ===== P2: LSTM activations (768 tasks) =====
    for (int task=tid; task<768; task+=512){
      int m=task>>8, rem=task&255, u=rem>>1, r=rem&1;
      const float* pm = s_p + m*2048 + r*512;
      const float* bl = s_bl[m];
      float g0 = bl[u]     + pm[u]     + pm[1024+u];
      float g1 = bl[128+u] + pm[128+u] + pm[1024+128+u];
      float g2 = bl[256+u] + pm[256+u] + pm[1024+256+u];
      float g3 = bl[384+u] + pm[384+u] + pm[1024+384+u];
      float ig=sigf(g0), fg=sigf(g1), gg=tanhf(g2), og=sigf(g3);
      float co = s_c2[(m*2+r)*128+u];
      float c  = fg*co + ig*gg;
      float h  = og*tanhf(c);
      s_c2[(m*2+r)*128+u]=c;
      s_h[(m*2+r)*128+u]=(_Float16)h;
      s_csf[r*768 + m*128+u]     = co;  s_cs[r*768 + m*128+u]     = (_Float16)co;
      s_csf[r*768 + 384+m*128+u] = c;   s_cs[r*768 + 384+m*128+u] = (_Float16)c;
    }
    __syncthreads();                               // B2

    // ===== P3: att1_W1 (256,768) on ALL 512 threads (cp128 x kh4, 24 units) =====
    {
      int cp=tid&127, kh=tid>>7;
      float a00=0.f,a01=0.f,a10=0.f,a11=0.f;
      sweep2<24,128>((const uint4*)p.a1w1 + kh*24*256 + cp*2, s_cs+kh*192, s_cs+768+kh*192, a00,a01,a10,a11);
      *(v2f*)&s_p[kh*512 +       2*cp] = (v2f){a00,a10};
      *(v2f*)&s_p[kh*512 + 256 + 2*cp] = (v2f){a01,a11};
    }
    __syncthreads();                               // B3

    // ===== P4: z1 finalize (4 kh segs) =====
    {
      int c=tid&255, r=tid>>8;
      float z = s_a1b1[c] + s_p[r*256+c] + s_p[512+r*256+c]
                          + s_p[1024+r*256+c] + s_p[1536+r*256+c];
      s_z[r*256+c] = (_Float16)fmaxf(z,0.f);
    }
    __syncthreads();                               // B4

    // ===== P5: att1_W2 (768,256): 384 pair-threads full-K; idle 128 prefetch x(t+1) =====
    if (tid < 384){
      float a00=0.f,a01=0.f,a10=0.f,a11=0.f;
      sweep2<32,384>((const uint4*)p.a1w2 + tid*2, s_z, s_z+256, a00,a01,a10,a11);
      *(v2f*)&s_p[      2*tid] = (v2f){a00,a10};
      *(v2f*)&s_p[768 + 2*tid] = (v2f){a01,a11};
    } else if (t+1 < TSTEPS){
      const float* __restrict__ xb = p.x + (size_t)(t+1)*NBATCH*DX;
      #pragma unroll
      for (int q=0;q<8;q++){
        int i2 = (tid-384) + q*128;
        int r=i2>>9, k=i2&511, f=xfeat(k);
        if (f>=0) s_x[i2] = (_Float16)xb[(size_t)(n0+r)*DX + f];
      }
    }
    __syncthreads();                               // B5

    // ===== softmax + attended =====
    {
      int col=tid&255, rr=tid>>8;
      float s0 = s_a1b2[col]     + s_p[rr*768+col];
      float s1 = s_a1b2[256+col] + s_p[rr*768+256+col];
      float s2 = s_a1b2[512+col] + s_p[rr*768+512+col];
      float mx=fmaxf(fmaxf(s0,s1),s2);
      for (int off=32; off; off>>=1) mx=fmaxf(mx,__shfl_down(mx,off));
      if ((tid&63)==0) s_red[tid>>6]=mx;
      __syncthreads();                             // B6
      float m = fmaxf(fmaxf(s_red[rr*4],s_red[rr*4+1]),fmaxf(s_red[rr*4+2],s_red[rr*4+3]));
      float e0=expf(s0-m), e1=expf(s1-m), e2=expf(s2-m);
      float ss=e0+e1+e2;
      for (int off=32; off; off>>=1) ss+=__shfl_down(ss,off);
      if ((tid&63)==0) s_red[8+(tid>>6)]=ss;
      s_at[rr*1024 + 768 + col] = (_Float16)s_mem[rr*256+col];
      __syncthreads();                             // B7
      float inv=1.f/(s_red[8+rr*4]+s_red[8+rr*4+1]+s_red[8+rr*4+2]+s_red[8+rr*4+3]);
      s_at[rr*1024 + col]       = (_Float16)(e0*inv*s_csf[rr*768+col]);
      s_at[rr*1024 + 256 + col] = (_Float16)(e1*inv*s_csf[rr*768+256+col]);
      s_at[rr*1024 + 512 + col] = (_Float16)(e2*inv*s_csf[rr*768+512+col]);
    }
    __syncthreads();                               // B8

    // ===== P7a: a2w1 (K=768) on 512 thr (cp128 x kh4, 24u) =====
    // ===== P7b: g1w1/g2w1 (K=1024) each on 256 thr (cp128 x kh2, 64u) =====
    {
      int cp=tid&127, kh4=tid>>7;
      float a00=0.f,a01=0.f,a10=0.f,a11=0.f;
      sweep2<24,128>((const uint4*)p.a2w1 + kh4*24*256 + cp*2, s_at+kh4*192, s_at+1024+kh4*192, a00,a01,a10,a11);
      *(v2f*)&s_p[kh4*512 +       2*cp] = (v2f){a00,a10};
      *(v2f*)&s_p[kh4*512 + 256 + 2*cp] = (v2f){a01,a11};
      int mg = tid>>8, kh = (tid>>7)&1;
      const _Float16* W = mg ? p.g2w1 : p.g1w1;
      a00=0.f;a01=0.f;a10=0.f;a11=0.f;
      sweep2<64,128>((const uint4*)W + kh*64*256 + cp*2, s_at+kh*512, s_at+1024+kh*512, a00,a01,a10,a11);
      *(v2f*)&s_p[2048 + mg*1024 + kh*512 +       2*cp] = (v2f){a00,a10};
      *(v2f*)&s_p[2048 + mg*1024 + kh*512 + 256 + 2*cp] = (v2f){a01,a11};
    }
    __syncthreads();                               // B9

    // ===== P8: z2 finalize (1536 tasks) =====
    for (int i=tid;i<1536;i+=512){
      int mu=i>>9, rem=i&511, r=rem>>8, c=rem&255;
      float v;
      if (mu==0)
        v = s_b6[0][c] + s_p[r*256+c] + s_p[512+r*256+c]
                       + s_p[1024+r*256+c] + s_p[1536+r*256+c];
      else {
        const float* q = s_p + 2048 + (mu-1)*1024;
        v = s_b6[mu][c] + q[r*256+c] + q[512+r*256+c];
      }
      s_z2[r*768 + mu*256 + c] = (_Float16)fmaxf(v,0.f);
    }
    __syncthreads();                               // B10

    // ===== P9: a2w2/g1w2/g2w2 (K=256 each); 3 groups x 128 pair-threads =====
    {
      int m4=tid>>7, cp=tid&127;
      if (m4<3){
        const _Float16* W = (m4==0)? p.a2w2 : ((m4==1)? p.g1w2 : p.g2w2);
        float a00=0.f,a01=0.f,a10=0.f,a11=0.f;
        sweep2<32,128>((const uint4*)W + cp*2, s_z2+m4*256, s_z2+768+m4*256, a00,a01,a10,a11);
        *(v2f*)&s_p[m4*512 +       2*cp] = (v2f){a00,a10};
        *(v2f*)&s_p[m4*512 + 256 + 2*cp] = (v2f){a01,a11};
      }
    }
    __syncthreads();                               // B11

    // ===== P10: mem update =====
    {
      int c=tid&255, r=tid>>8;
      float ch  = s_b6[3][c] + s_p[r*256+c];
      float gm1 = s_b6[4][c] + s_p[512 + r*256+c];
      float gm2 = s_b6[5][c] + s_p[1024 + r*256+c];
      float mo = s_mem[r*256+c];
      s_mem[r*256+c] = sigf(gm1)*mo + sigf(gm2)*tanhf(ch);
    }
    __syncthreads();                               // B12
  }

  // ===== output MLP (K=640) =====
  for (int i=tid;i<1280;i+=512){
    int r=(i>=640)?1:0, j=i-r*640;
    _Float16 v = (j<384)? s_h[((j>>7)*2+r)*128 + (j&127)] : (_Float16)s_mem[r*256+(j-384)];
    s_last[r*640+j]=v;
  }
  __syncthreads();
  if (tid < 256){
    int cp=tid&127, kh=tid>>7;
    float a00=0.f,a01=0.f,a10=0.f,a11=0.f;
    sweep2<40,128>((const uint4*)p.ow1 + kh*40*256 + cp*2, s_last+kh*320, s_last+640+kh*320, a00,a01,a10,a11);
    *(v2f*)&s_p[kh*512 +       2*cp] = (v2f){a00,a10};
    *(v2f*)&s_p[kh*512 + 256 + 2*cp] = (v2f){a01,a11};
  }
  __syncthreads();
  {
    int c=tid&255, rr=tid>>8;
    float z = p.ob1[c] + s_p[rr*256+c] + s_p[512+rr*256+c];
    float pp = fmaxf(z,0.f)*p.ow2[c];
    for (int off=32; off; off>>=1) pp+=__shfl_down(pp,off);
    if ((tid&63)==0) s_red[tid>>6]=pp;
    __syncthreads();
    if (tid==0)   p.out[n0]   = s_red[0]+s_red[1]+s_red[2]+s_red[3]+p.ob2[0];
    if (tid==256) p.out[n0+1] = s_red[4]+s_red[5]+s_red[6]+s_red[7]+p.ob2[0];
  }
}

extern "C" void kernel_launch(void* const* d_in, const int* in_sizes, int n_in,
                              void* d_out, int out_size, void* d_ws, size_t ws_size,
                              hipStream_t stream){
  _Float16* ws = (_Float16*)d_ws;
  struct M { int src; size_t off; int OUT, IN, INP; };
  const M mats[15] = {
    { 5,       0, 512,  300, 320},  // Wih_l
    { 6,  163840, 512,  128, 128},  // Whh_l
    { 9,  229376, 512,   74, 128},  // Wih_a
    {10,  294912, 512,  128, 128},  // Whh_a
    {13,  360448, 512,   35,  64},  // Wih_v
    {14,  393216, 512,  128, 128},  // Whh_v
    {17,  458752, 256,  768, 768},  // att1_W1
    {19,  655360, 768,  256, 256},  // att1_W2
    {21,  851968, 256,  768, 768},  // att2_W1
    {23, 1048576, 256,  256, 256},  // att2_W2
    {25, 1114112, 256, 1024,1024},  // g1_W1
    {27, 1376256, 256,  256, 256},  // g1_W2
    {29, 1441792, 256, 1024,1024},  // g2_W1
    {31, 1703936, 256,  256, 256},  // g2_W2
    {33, 1769472, 256,  640, 640},  // out_W1
  };
  for (int i=0;i<15;i++){
    int total = mats[i].OUT*mats[i].INP;
    cast_pair<<<(total+255)/256, 256, 0, stream>>>(
        (const float*)d_in[mats[i].src], ws + mats[i].off,
        mats[i].OUT, mats[i].IN, mats[i].INP);
  }

  P p;
  p.x     = (const float*)d_in[0];
  p.bih_l = (const float*)d_in[7];  p.bhh_l = (const float*)d_in[8];
  p.bih_a = (const float*)d_in[11]; p.bhh_a = (const float*)d_in[12];
  p.bih_v = (const float*)d_in[15]; p.bhh_v = (const float*)d_in[16];
  p.a1b1  = (const float*)d_in[18]; p.a1b2  = (const float*)d_in[20];
  p.a2b1  = (const float*)d_in[22]; p.a2b2  = (const float*)d_in[24];
  p.g1b1  = (const float*)d_in[26]; p.g1b2  = (const float*)d_in[28];
  p.g2b1  = (const float*)d_in[30]; p.g2b2  = (const float*)d_in[32];
  p.ob1   = (const float*)d_in[34]; p.ow2   = (const float*)d_in[35];
  p.ob2   = (const float*)d_in[36];
  p.ihl   = ws + 0;       p.hhl  = ws + 163840;
  p.iha   = ws + 229376;  p.hha  = ws + 294912;
  p.ihv   = ws + 360448;  p.hhv  = ws + 393216;
  p.a1w1  = ws + 458752;  p.a1w2 = ws + 655360;
  p.a2w1  = ws + 851968;  p.a2w2 = ws + 1048576;
  p.g1w1  = ws + 1114112; p.g1w2 = ws + 1376256;
  p.g2w1  = ws + 1441792; p.g2w2 = ws + 1703936;
  p.ow1   = ws + 1769472;
  p.out   = (float*)d_out;

  mfn_persistent<<<NBATCH/2, 512, 0, stream>>>(p);
}